// Round 18
// baseline (3214.673 us; speedup 1.0000x reference)
//
#include <hip/hip_runtime.h>
#include <hip/hip_bf16.h>

typedef long long TLONG;
typedef float  f32x4_t  __attribute__((ext_vector_type(4)));
typedef short  s16x8_t  __attribute__((ext_vector_type(8)));
typedef short  s16x4_t  __attribute__((ext_vector_type(4)));
typedef __bf16 bf16x8_t __attribute__((ext_vector_type(8)));

#define MDIM 32768
#define NDIM 1024
#define KDIM 1024
#define EPSV 1e-6f

#define BARRIER() asm volatile("s_barrier" ::: "memory")
#define SBAR() __builtin_amdgcn_sched_barrier(0)

__device__ __forceinline__ unsigned short f2bf_bits(float f) {
  __hip_bfloat16 h = __float2bfloat16(f);
  return __builtin_bit_cast(unsigned short, h);
}
__device__ __forceinline__ float bf2f(unsigned short u) {
  unsigned int x = ((unsigned int)u) << 16;
  return __builtin_bit_cast(float, x);
}
// async global->LDS, 16B per lane. LDS dest must be wave-uniform base + lane*16.
__device__ __forceinline__ void load_lds16(const void* g, void* l) {
  __builtin_amdgcn_global_load_lds((const __attribute__((address_space(1))) void*)g,
                                   (__attribute__((address_space(3))) void*)l, 16, 0, 0);
}

// nt LOADS (f32 read exactly once -> keep out of L3); REGULAR stores (outputs
// re-read by GEMMs -> want L3 residency). [R8: nt stores cost +26MB refetch]
__device__ __forceinline__ void conv8(const float* __restrict__ in,
                                      unsigned short* __restrict__ out, TLONG i) {
  f32x4_t a = __builtin_nontemporal_load(reinterpret_cast<const f32x4_t*>(in + i));
  f32x4_t b = __builtin_nontemporal_load(reinterpret_cast<const f32x4_t*>(in + i + 4));
  s16x8_t o;
  o[0] = (short)f2bf_bits(a[0]); o[1] = (short)f2bf_bits(a[1]);
  o[2] = (short)f2bf_bits(a[2]); o[3] = (short)f2bf_bits(a[3]);
  o[4] = (short)f2bf_bits(b[0]); o[5] = (short)f2bf_bits(b[1]);
  o[6] = (short)f2bf_bits(b[2]); o[7] = (short)f2bf_bits(b[3]);
  *reinterpret_cast<s16x8_t*>(out + i) = o;
}

// ---------------------------------------------------------------- merged convert
__global__ __launch_bounds__(256) void convert_all_f32_bf16(
    const float* __restrict__ q, const float* __restrict__ k, const float* __restrict__ v,
    const float* __restrict__ wq, const float* __restrict__ wk,
    const float* __restrict__ wv, const float* __restrict__ wo,
    unsigned short* __restrict__ oq, unsigned short* __restrict__ ok,
    unsigned short* __restrict__ ov, unsigned short* __restrict__ owq,
    unsigned short* __restrict__ owk, unsigned short* __restrict__ owv,
    unsigned short* __restrict__ owo) {
  int blk = blockIdx.x;
  if (blk < 6144) {
    const float* in; unsigned short* out;
    if (blk < 2048)      { in = q; out = oq; }
    else if (blk < 4096) { in = k; out = ok; blk -= 2048; }
    else                 { in = v; out = ov; blk -= 4096; }
    const TLONG n = 33554432LL;
    TLONG i = ((TLONG)blk * 256 + threadIdx.x) * 8;
    const TLONG stride = 2048LL * 256 * 8;
    for (; i < n; i += stride) conv8(in, out, i);
  } else {
    blk -= 6144;
    const float* in; unsigned short* out;
    if (blk < 512)       { in = wq; out = owq; }
    else if (blk < 1024) { in = wk; out = owk; blk -= 512; }
    else if (blk < 1536) { in = wv; out = owv; blk -= 1024; }
    else                 { in = wo; out = owo; blk -= 1536; }
    TLONG i = ((TLONG)blk * 256 + threadIdx.x) * 8;
    conv8(in, out, i);
  }
}

// ---------------------------------------------------------------- QKV GEMM, BK=32, 2 blocks/CU
// 1536 blocks = 3 segs x 512. Counted ladder (R15-proven discipline) on a
// 256x256 tile with BK=32: LDS 64KB = 2buf x (A 16KB | B 16KB) -> 2 blocks/CU.
// Same wave tile (128x64) and LDS-read:MFMA ratio as R15; mechanism = m114
// inter-block overlap of barrier/wait stalls. 32 K-tiles, 3 barriers each.
// Swizzle unit = 2 rows (128B): slot (4*(row&1)+lh) ^ (pair&7) -> 2-way max.
// Per-tile loads [B(kt+1) x2, A(kt+2) x2]; vmcnt(2) retires buf-q exactly.
__global__ __launch_bounds__(512, 4) void gemm_qkv(
    const unsigned short* __restrict__ Aq, const unsigned short* __restrict__ Ak,
    const unsigned short* __restrict__ Av,
    const unsigned short* __restrict__ Wq, const unsigned short* __restrict__ Wk,
    const unsigned short* __restrict__ Wv,
    const float* __restrict__ bq, const float* __restrict__ bk,
    const float* __restrict__ bv,
    unsigned short* __restrict__ Cq, unsigned short* __restrict__ Ck,
    unsigned short* __restrict__ Cv) {
  __shared__ short lds[32768];                    // 64KB: [2 buf][A 8192 | B 8192]
  const int seg = blockIdx.x >> 9;                // 0,1,2
  const int local = blockIdx.x & 511;
  const unsigned short* A;
  const unsigned short* W;
  const float* bias;
  unsigned short* Cout;
  int fmap, outMode;
  if (seg == 0)      { A = Aq; W = Wq; bias = bq; Cout = Cq; fmap = 1; outMode = 0; }
  else if (seg == 1) { A = Ak; W = Wk; bias = bk; Cout = Ck; fmap = 1; outMode = 2; }
  else               { A = Av; W = Wv; bias = bv; Cout = Cv; fmap = 0; outMode = 2; }

  const int swz = (local & 7) * 64 + (local >> 3);  // XCD-chunked (512%8==0)
  const int mt = swz >> 2;
  const int nt = swz & 3;

  const int tid = threadIdx.x;
  const int lane = tid & 63;
  const int w = tid >> 6;
  const int wr = w >> 2, wc = w & 3;
  const int l15 = lane & 15, lh = lane >> 4;

  const int arow0 = mt * 256, brow0 = nt * 256;

  // stage one 256x32 tile (16KB = 1024 x 16B chunks, 2/thread), linear LDS dest,
  // inverse pair-swizzled source: chunk c -> pair=c>>3, slot ps=c&7,
  // sg = ps^(pair&7); global (row = 2*pair+(sg>>2), kgroup = sg&3).
  auto stage_mat = [&](const unsigned short* __restrict__ src, int ldsOff,
                       int grow, int k0) {
#pragma unroll
    for (int i = 0; i < 2; ++i) {
      const int c = i * 512 + tid;                // 0..1023
      const int pr = c >> 3, ps = c & 7;
      const int sg = ps ^ (pr & 7);
      load_lds16(src + (grow + pr * 2 + (sg >> 2)) * KDIM + k0 + ((sg & 3) * 8),
                 &lds[ldsOff + c * 8]);
    }
  };

  f32x4_t acc[8][4];
#pragma unroll
  for (int m = 0; m < 8; ++m)
#pragma unroll
    for (int n = 0; n < 4; ++n) acc[m][n] = (f32x4_t)0.0f;

  s16x8_t Af[8], Bf[4];

  auto rdA = [&](int pb, int m) -> s16x8_t {
    const int row = wr * 128 + m * 16 + l15;
    const int pr = row >> 1;
    const int slot = ((row & 1) * 4 + lh) ^ (pr & 7);
    return *reinterpret_cast<const s16x8_t*>(&lds[pb + pr * 64 + slot * 8]);
  };
  auto rdB = [&](int pb, int n) -> s16x8_t {
    const int row = wc * 64 + n * 16 + l15;
    const int pr = row >> 1;
    const int slot = ((row & 1) * 4 + lh) ^ (pr & 7);
    return *reinterpret_cast<const s16x8_t*>(&lds[pb + 8192 + pr * 64 + slot * 8]);
  };
  auto quad = [&](int nl) {                       // all A x B[nl..nl+1]: 16 MFMA
    __builtin_amdgcn_s_setprio(1);
#pragma unroll
    for (int m = 0; m < 8; ++m)
#pragma unroll
      for (int n = 0; n < 2; ++n)
        acc[m][nl + n] = __builtin_amdgcn_mfma_f32_16x16x32_bf16(
            __builtin_bit_cast(bf16x8_t, Af[m]),
            __builtin_bit_cast(bf16x8_t, Bf[nl + n]),
            acc[m][nl + n], 0, 0, 0);
    __builtin_amdgcn_s_setprio(0);
  };

  // prologue: A(0),B(0) -> buf0; A(1) -> buf1.A (6 loads/thread)
  stage_mat(A, 0,     arow0, 0);
  stage_mat(W, 8192,  brow0, 0);
  stage_mat(A, 16384, arow0, 32);
  asm volatile("s_waitcnt vmcnt(2)" ::: "memory");   // A(0),B(0) landed; A(1) flying
  SBAR();
  BARRIER();

  for (int kt = 0; kt < 32; ++kt) {
    const int p = kt & 1;
    const int pb = p * 16384, qb = 16384 - pb;
    const int k1 = ((kt + 1) & 31) * 32;
    const int k2 = ((kt + 2) & 31) * 32;   // wrapped tail: junk reload, never read
    // ---- P1: reads pinned [10 | 2]; stage B(kt+1) -> buf q.B
#pragma unroll
    for (int m = 0; m < 8; ++m) Af[m] = rdA(pb, m);
#pragma unroll
    for (int n = 0; n < 2; ++n) Bf[n] = rdB(pb, n);
    SBAR();                                         // group 1 (10 reads)
#pragma unroll
    for (int n = 2; n < 4; ++n) Bf[n] = rdB(pb, n);
    SBAR();                                         // group 2 (2 reads)
    stage_mat(W, qb + 8192, brow0, k1);
    BARRIER();
    asm volatile("s_waitcnt lgkmcnt(2)" ::: "memory");   // group 1 done
    SBAR();
    quad(0);
    BARRIER();                                      // block-wide: Af readers retired
    // ---- P2: stage A(kt+2) -> buf p.A; counted waits
    stage_mat(A, pb, arow0, k2);
    asm volatile("s_waitcnt lgkmcnt(0)" ::: "memory");   // group 2 (Bf2-3) done
    SBAR();
    quad(2);
    asm volatile("s_waitcnt vmcnt(2)" ::: "memory");     // A(kt+1),B(kt+1) landed
    SBAR();
    BARRIER();
  }

  // epilogue: C/D layout col = lane&15, row = (lane>>4)*4 + j  [m89/m91]
#pragma unroll
  for (int n = 0; n < 4; ++n) {
    const int col = nt * 256 + wc * 64 + n * 16 + l15;
    const float bv2 = bias[col];
#pragma unroll
    for (int m = 0; m < 8; ++m) {
      const int row0 = mt * 256 + wr * 128 + m * 16 + lh * 4;
      if (outMode == 2) {
        const int b = row0 >> 13, tl = row0 & 8191;
        const int h = col >> 6, d = col & 63;
        s16x4_t o;
#pragma unroll
        for (int j = 0; j < 4; ++j) {
          float v = acc[m][n][j] + bv2;
          if (fmap) v = (v > 0.0f) ? (v + 1.0f) : __expf(v);
          o[j] = (short)f2bf_bits(v);
        }
        *reinterpret_cast<s16x4_t*>(Cout + (((b * 16 + h) * 64 + d) * 8192 + tl)) = o;
      } else {
#pragma unroll
        for (int j = 0; j < 4; ++j) {
          float v = acc[m][n][j] + bv2;
          if (fmap) v = (v > 0.0f) ? (v + 1.0f) : __expf(v);  // elu(x)+1
          Cout[(row0 + j) * NDIM + col] = f2bf_bits(v);
        }
      }
    }
  }
}

// ---------------------------------------------------------------- final GEMM, BK=32, 2 blocks/CU
__global__ __launch_bounds__(512, 4) void gemm_out(
    const unsigned short* __restrict__ A, const unsigned short* __restrict__ W,
    const float* __restrict__ bias, float* __restrict__ Cout) {
  __shared__ short lds[32768];
  const int bid = blockIdx.x;                     // 512 blocks
  const int swz = (bid & 7) * 64 + (bid >> 3);
  const int mt = swz >> 2;
  const int nt = swz & 3;

  const int tid = threadIdx.x;
  const int lane = tid & 63;
  const int w = tid >> 6;
  const int wr = w >> 2, wc = w & 3;
  const int l15 = lane & 15, lh = lane >> 4;

  const int arow0 = mt * 256, brow0 = nt * 256;

  auto stage_mat = [&](const unsigned short* __restrict__ src, int ldsOff,
                       int grow, int k0) {
#pragma unroll
    for (int i = 0; i < 2; ++i) {
      const int c = i * 512 + tid;
      const int pr = c >> 3, ps = c & 7;
      const int sg = ps ^ (pr & 7);
      load_lds16(src + (grow + pr * 2 + (sg >> 2)) * KDIM + k0 + ((sg & 3) * 8),
                 &lds[ldsOff + c * 8]);
    }
  };

  f32x4_t acc[8][4];
#pragma unroll
  for (int m = 0; m < 8; ++m)
#pragma unroll
    for (int n = 0; n < 4; ++n) acc[m][n] = (f32x4_t)0.0f;

  s16x8_t Af[8], Bf[4];

  auto rdA = [&](int pb, int m) -> s16x8_t {
    const int row = wr * 128 + m * 16 + l15;
    const int pr = row >> 1;
    const int slot = ((row & 1) * 4 + lh) ^ (pr & 7);
    return *reinterpret_cast<const s16x8_t*>(&lds[pb + pr * 64 + slot * 8]);
  };
  auto rdB = [&](int pb, int n) -> s16x8_t {
    const int row = wc * 64 + n * 16 + l15;
    const int pr = row >> 1;
    const int slot = ((row & 1) * 4 + lh) ^ (pr & 7);
    return *reinterpret_cast<const s16x8_t*>(&lds[pb + 8192 + pr * 64 + slot * 8]);
  };
  auto quad = [&](int nl) {
    __builtin_amdgcn_s_setprio(1);
#pragma unroll
    for (int m = 0; m < 8; ++m)
#pragma unroll
      for (int n = 0; n < 2; ++n)
        acc[m][nl + n] = __builtin_amdgcn_mfma_f32_16x16x32_bf16(
            __builtin_bit_cast(bf16x8_t, Af[m]),
            __builtin_bit_cast(bf16x8_t, Bf[nl + n]),
            acc[m][nl + n], 0, 0, 0);
    __builtin_amdgcn_s_setprio(0);
  };

  stage_mat(A, 0,     arow0, 0);
  stage_mat(W, 8192,  brow0, 0);
  stage_mat(A, 16384, arow0, 32);
  asm volatile("s_waitcnt vmcnt(2)" ::: "memory");
  SBAR();
  BARRIER();

  for (int kt = 0; kt < 32; ++kt) {
    const int p = kt & 1;
    const int pb = p * 16384, qb = 16384 - pb;
    const int k1 = ((kt + 1) & 31) * 32;
    const int k2 = ((kt + 2) & 31) * 32;
#pragma unroll
    for (int m = 0; m < 8; ++m) Af[m] = rdA(pb, m);
#pragma unroll
    for (int n = 0; n < 2; ++n) Bf[n] = rdB(pb, n);
    SBAR();
#pragma unroll
    for (int n = 2; n < 4; ++n) Bf[n] = rdB(pb, n);
    SBAR();
    stage_mat(W, qb + 8192, brow0, k1);
    BARRIER();
    asm volatile("s_waitcnt lgkmcnt(2)" ::: "memory");
    SBAR();
    quad(0);
    BARRIER();
    stage_mat(A, pb, arow0, k2);
    asm volatile("s_waitcnt lgkmcnt(0)" ::: "memory");
    SBAR();
    quad(2);
    asm volatile("s_waitcnt vmcnt(2)" ::: "memory");
    SBAR();
    BARRIER();
  }

#pragma unroll
  for (int n = 0; n < 4; ++n) {
    const int col = nt * 256 + wc * 64 + n * 16 + l15;
    const float bv = bias[col];
#pragma unroll
    for (int m = 0; m < 8; ++m) {
      const int row0 = mt * 256 + wr * 128 + m * 16 + lh * 4;
#pragma unroll
      for (int j = 0; j < 4; ++j)
        __builtin_nontemporal_store(acc[m][n][j] + bv,   // final f32: never re-read
                                    &Cout[(row0 + j) * NDIM + col]);
    }
  }
}

// ---------------------------------------------------------------- kv + k_sum (MFMA, streaming)
__global__ __launch_bounds__(256) void kv_ksum_mfma(
    const unsigned short* __restrict__ kT, const unsigned short* __restrict__ vT,
    float* __restrict__ kvT, float* __restrict__ ksum) {
  const int bid = blockIdx.x;
  const int bh = bid >> 4, ch = bid & 15;
  const int tid = threadIdx.x;
  const int lane = tid & 63, w = tid >> 6;
  const int l15 = lane & 15, lh = lane >> 4;
  const int dblk = (w >> 1) * 32, eblk = (w & 1) * 32;

  f32x4_t acc[2][2];
#pragma unroll
  for (int m = 0; m < 2; ++m)
#pragma unroll
    for (int n = 0; n < 2; ++n) acc[m][n] = (f32x4_t)0.0f;
  float ks0 = 0.f, ks1 = 0.f;

  const int tbase = ch * 512 + lh * 8;
  const unsigned short* ka = kT + (bh * 64 + dblk + l15) * 8192 + tbase;
  const unsigned short* va = vT + (bh * 64 + eblk + l15) * 8192 + tbase;

  for (int t0 = 0; t0 < 512; t0 += 32) {
    s16x8_t ar[2], br[2];
#pragma unroll
    for (int m = 0; m < 2; ++m)
      ar[m] = *reinterpret_cast<const s16x8_t*>(ka + m * 16 * 8192 + t0);
#pragma unroll
    for (int n = 0; n < 2; ++n)
      br[n] = *reinterpret_cast<const s16x8_t*>(va + n * 16 * 8192 + t0);
#pragma unroll
    for (int m = 0; m < 2; ++m)
#pragma unroll
      for (int n = 0; n < 2; ++n)
        acc[m][n] = __builtin_amdgcn_mfma_f32_16x16x32_bf16(
            __builtin_bit_cast(bf16x8_t, ar[m]),
            __builtin_bit_cast(bf16x8_t, br[n]), acc[m][n], 0, 0, 0);
    if (eblk == 0) {
#pragma unroll
      for (int i = 0; i < 8; ++i) ks0 += bf2f((unsigned short)ar[0][i]);
#pragma unroll
      for (int i = 0; i < 8; ++i) ks1 += bf2f((unsigned short)ar[1][i]);
    }
  }

  if (eblk == 0) {
    ks0 += __shfl_xor(ks0, 16); ks0 += __shfl_xor(ks0, 32);
    ks1 += __shfl_xor(ks1, 16); ks1 += __shfl_xor(ks1, 32);
    if (lh == 0) {
      atomicAdd(&ksum[bh * 64 + dblk + l15], ks0);
      atomicAdd(&ksum[bh * 64 + dblk + 16 + l15], ks1);
    }
  }
#pragma unroll
  for (int n = 0; n < 2; ++n) {
    const int e = eblk + n * 16 + l15;
#pragma unroll
    for (int m = 0; m < 2; ++m) {
      const int d0 = dblk + m * 16 + lh * 4;
#pragma unroll
      for (int j = 0; j < 4; ++j)
        atomicAdd(&kvT[(bh * 64 + e) * 64 + d0 + j], acc[m][n][j]);
    }
  }
}

// ---------------------------------------------------------------- out = q@kv / (q.ksum+eps)
__global__ __launch_bounds__(256) void attn_apply_kernel(
    const unsigned short* __restrict__ qf, const float* __restrict__ kvT,
    const float* __restrict__ ksum, unsigned short* __restrict__ att) {
  const int bid = blockIdx.x;                     // 2048
  const int swz = (bid & 7) * 256 + (bid >> 3);
  const int bh = swz >> 5;
  const int tile = swz & 31;
  const int b = bh >> 4, h = bh & 15;
  const int tid = threadIdx.x;
  const int lane = tid & 63, w = tid >> 6;
  const int l15 = lane & 15, lh = lane >> 4;

  float ksr[16];
#pragma unroll
  for (int i = 0; i < 16; ++i) ksr[i] = ksum[bh * 64 + lh * 16 + i];

  bf16x8_t bfrag[2][4];
#pragma unroll
  for (int ks2 = 0; ks2 < 2; ++ks2)
#pragma unroll
    for (int n = 0; n < 4; ++n) {
      const float* p = kvT + (bh * 64 + n * 16 + l15) * 64 + ks2 * 32 + lh * 8;
      f32x4_t p0 = *reinterpret_cast<const f32x4_t*>(p);
      f32x4_t p1 = *reinterpret_cast<const f32x4_t*>(p + 4);
      s16x8_t t;
      t[0] = (short)f2bf_bits(p0[0]); t[1] = (short)f2bf_bits(p0[1]);
      t[2] = (short)f2bf_bits(p0[2]); t[3] = (short)f2bf_bits(p0[3]);
      t[4] = (short)f2bf_bits(p1[0]); t[5] = (short)f2bf_bits(p1[1]);
      t[6] = (short)f2bf_bits(p1[2]); t[7] = (short)f2bf_bits(p1[3]);
      bfrag[ks2][n] = __builtin_bit_cast(bf16x8_t, t);
    }

  const int rbase = b * 8192 + tile * 256 + w * 64;
  f32x4_t acc[4][4];
#pragma unroll
  for (int m = 0; m < 4; ++m)
#pragma unroll
    for (int n = 0; n < 4; ++n) acc[m][n] = (f32x4_t)0.0f;
  float rden[4][4];

#pragma unroll
  for (int m = 0; m < 4; ++m) {
    const int row = rbase + m * 16 + l15;
    const unsigned short* qrow = qf + row * 1024 + h * 64;
    bf16x8_t afr[2];
#pragma unroll
    for (int ks2 = 0; ks2 < 2; ++ks2)
      afr[ks2] = __builtin_bit_cast(bf16x8_t,
          *reinterpret_cast<const s16x8_t*>(qrow + ks2 * 32 + lh * 8));
    s16x8_t qa = *reinterpret_cast<const s16x8_t*>(qrow + lh * 16);
    s16x8_t qb = *reinterpret_cast<const s16x8_t*>(qrow + lh * 16 + 8);
    float part = 0.f;
#pragma unroll
    for (int i = 0; i < 8; ++i) part += bf2f((unsigned short)qa[i]) * ksr[i];
#pragma unroll
    for (int i = 0; i < 8; ++i) part += bf2f((unsigned short)qb[i]) * ksr[8 + i];
    part += __shfl_xor(part, 16);
    part += __shfl_xor(part, 32);
#pragma unroll
    for (int j = 0; j < 4; ++j) {
      float dj = __shfl(part, lh * 4 + j);
      rden[m][j] = 1.0f / (dj + EPSV);
    }
#pragma unroll
    for (int ks2 = 0; ks2 < 2; ++ks2)
#pragma unroll
      for (int n = 0; n < 4; ++n)
        acc[m][n] = __builtin_amdgcn_mfma_f32_16x16x32_bf16(afr[ks2], bfrag[ks2][n], acc[m][n], 0, 0, 0);
  }

#pragma unroll
  for (int m = 0; m < 4; ++m)
#pragma unroll
    for (int n = 0; n < 4; ++n) {
      const int col = h * 64 + n * 16 + l15;
#pragma unroll
      for (int j = 0; j < 4; ++j) {
        const int row = rbase + m * 16 + lh * 4 + j;
        att[row * 1024 + col] = f2bf_bits(acc[m][n][j] * rden[m][j]);
      }
    }
}

// ---------------------------------------------------------------- launch
extern "C" void kernel_launch(void* const* d_in, const int* in_sizes, int n_in,
                              void* d_out, int out_size, void* d_ws, size_t ws_size,
                              hipStream_t stream) {
  const float* query = (const float*)d_in[0];
  const float* key   = (const float*)d_in[1];
  const float* value = (const float*)d_in[2];
  const float* Wq = (const float*)d_in[3];
  const float* bq = (const float*)d_in[4];
  const float* Wk = (const float*)d_in[5];
  const float* bk = (const float*)d_in[6];
  const float* Wv = (const float*)d_in[7];
  const float* bv = (const float*)d_in[8];
  const float* Wo = (const float*)d_in[9];
  const float* bo = (const float*)d_in[10];
  float* out = (float*)d_out;

  if (ws_size < 277889024ULL) return;
  char* ws = (char*)d_ws;
  unsigned short* Vbf = (unsigned short*)(ws + 0);          // value bf16; reused as att
  unsigned short* qf  = (unsigned short*)(ws + 67108864);
  unsigned short* kTf = (unsigned short*)(ws + 134217728);  // k transposed [b][h][d][t]
  unsigned short* vTf = (unsigned short*)(ws + 201326592);  // v transposed
  unsigned short* Wqb = (unsigned short*)(ws + 268435456);
  unsigned short* Wkb = Wqb + 1048576;
  unsigned short* Wvb = Wkb + 1048576;
  unsigned short* Wob = Wvb + 1048576;
  float* kvT  = (float*)(ws + 276824064);
  float* ksum = (float*)(ws + 277872640);

  unsigned short* Qbf = (unsigned short*)d_out;   // d_out doubles as bf16 scratch
  unsigned short* Kbf = Qbf + 33554432;

  hipMemsetAsync(kvT, 0, (size_t)(64 * 64 * 64 + 64 * 64) * sizeof(float), stream);

  convert_all_f32_bf16<<<8192, 256, 0, stream>>>(
      query, key, value, Wq, Wk, Wv, Wo,
      Qbf, Kbf, Vbf, Wqb, Wkb, Wvb, Wob);

  gemm_qkv<<<1536, 512, 0, stream>>>(Qbf, Kbf, Vbf, Wqb, Wkb, Wvb,
                                     bq, bk, bv, qf, kTf, vTf);

  kv_ksum_mfma<<<1024, 256, 0, stream>>>(kTf, vTf, kvT, ksum);

  attn_apply_kernel<<<2048, 256, 0, stream>>>(qf, kvT, ksum, Vbf);  // att -> Vbf

  gemm_out<<<512, 512, 0, stream>>>(Vbf, Wob, bo, out);  // final -> f32
}

// Round 19
// 565.001 us; speedup vs baseline: 5.6897x; 5.6897x over previous
//
#include <hip/hip_runtime.h>
#include <hip/hip_bf16.h>

typedef long long TLONG;
typedef float  f32x4_t  __attribute__((ext_vector_type(4)));
typedef short  s16x8_t  __attribute__((ext_vector_type(8)));
typedef short  s16x4_t  __attribute__((ext_vector_type(4)));
typedef __bf16 bf16x8_t __attribute__((ext_vector_type(8)));

#define MDIM 32768
#define NDIM 1024
#define KDIM 1024
#define EPSV 1e-6f

#define BARRIER() asm volatile("s_barrier" ::: "memory")
#define SBAR() __builtin_amdgcn_sched_barrier(0)

__device__ __forceinline__ unsigned short f2bf_bits(float f) {
  __hip_bfloat16 h = __float2bfloat16(f);
  return __builtin_bit_cast(unsigned short, h);
}
__device__ __forceinline__ float bf2f(unsigned short u) {
  unsigned int x = ((unsigned int)u) << 16;
  return __builtin_bit_cast(float, x);
}
// async global->LDS, 16B per lane. LDS dest must be wave-uniform base + lane*16.
__device__ __forceinline__ void load_lds16(const void* g, void* l) {
  __builtin_amdgcn_global_load_lds((const __attribute__((address_space(1))) void*)g,
                                   (__attribute__((address_space(3))) void*)l, 16, 0, 0);
}

// nt LOADS (f32 read exactly once -> keep out of L3); REGULAR stores (outputs
// re-read by GEMMs -> want L3 residency). [R8: nt stores cost +26MB refetch]
__device__ __forceinline__ void conv8(const float* __restrict__ in,
                                      unsigned short* __restrict__ out, TLONG i) {
  f32x4_t a = __builtin_nontemporal_load(reinterpret_cast<const f32x4_t*>(in + i));
  f32x4_t b = __builtin_nontemporal_load(reinterpret_cast<const f32x4_t*>(in + i + 4));
  s16x8_t o;
  o[0] = (short)f2bf_bits(a[0]); o[1] = (short)f2bf_bits(a[1]);
  o[2] = (short)f2bf_bits(a[2]); o[3] = (short)f2bf_bits(a[3]);
  o[4] = (short)f2bf_bits(b[0]); o[5] = (short)f2bf_bits(b[1]);
  o[6] = (short)f2bf_bits(b[2]); o[7] = (short)f2bf_bits(b[3]);
  *reinterpret_cast<s16x8_t*>(out + i) = o;
}

// ---------------------------------------------------------------- merged convert
__global__ __launch_bounds__(256) void convert_all_f32_bf16(
    const float* __restrict__ q, const float* __restrict__ k, const float* __restrict__ v,
    const float* __restrict__ wq, const float* __restrict__ wk,
    const float* __restrict__ wv, const float* __restrict__ wo,
    unsigned short* __restrict__ oq, unsigned short* __restrict__ ok,
    unsigned short* __restrict__ ov, unsigned short* __restrict__ owq,
    unsigned short* __restrict__ owk, unsigned short* __restrict__ owv,
    unsigned short* __restrict__ owo) {
  int blk = blockIdx.x;
  if (blk < 6144) {
    const float* in; unsigned short* out;
    if (blk < 2048)      { in = q; out = oq; }
    else if (blk < 4096) { in = k; out = ok; blk -= 2048; }
    else                 { in = v; out = ov; blk -= 4096; }
    const TLONG n = 33554432LL;
    TLONG i = ((TLONG)blk * 256 + threadIdx.x) * 8;
    const TLONG stride = 2048LL * 256 * 8;
    for (; i < n; i += stride) conv8(in, out, i);
  } else {
    blk -= 6144;
    const float* in; unsigned short* out;
    if (blk < 512)       { in = wq; out = owq; }
    else if (blk < 1024) { in = wk; out = owk; blk -= 512; }
    else if (blk < 1536) { in = wv; out = owv; blk -= 1024; }
    else                 { in = wo; out = owo; blk -= 1536; }
    TLONG i = ((TLONG)blk * 256 + threadIdx.x) * 8;
    conv8(in, out, i);
  }
}

// ---------------------------------------------------------------- merged QKV GEMM (R15 verbatim)
// 1536 blocks = 3 segments x 512. seg 0: q = fmap(query@Wq^T) row-major;
// seg 1: k = fmap(key@Wk^T) transposed; seg 2: v = value@Wv^T transposed.
// Hot loop = measured-best counted ladder (lgkm 12/4/0, one vmcnt(4)/tile).
__global__ __launch_bounds__(512, 2) void gemm_qkv(
    const unsigned short* __restrict__ Aq, const unsigned short* __restrict__ Ak,
    const unsigned short* __restrict__ Av,
    const unsigned short* __restrict__ Wq, const unsigned short* __restrict__ Wk,
    const unsigned short* __restrict__ Wv,
    const float* __restrict__ bq, const float* __restrict__ bk,
    const float* __restrict__ bv,
    unsigned short* __restrict__ Cq, unsigned short* __restrict__ Ck,
    unsigned short* __restrict__ Cv) {
  __shared__ short lds[65536];                    // [2 buf][A 16384 | B 16384] shorts
  const int seg = blockIdx.x >> 9;                // 0,1,2
  const int local = blockIdx.x & 511;
  const unsigned short* A;
  const unsigned short* W;
  const float* bias;
  unsigned short* Cout;
  int fmap, outMode;
  if (seg == 0)      { A = Aq; W = Wq; bias = bq; Cout = Cq; fmap = 1; outMode = 0; }
  else if (seg == 1) { A = Ak; W = Wk; bias = bk; Cout = Ck; fmap = 1; outMode = 2; }
  else               { A = Av; W = Wv; bias = bv; Cout = Cv; fmap = 0; outMode = 2; }

  const int swz = (local & 7) * 64 + (local >> 3);  // XCD-chunked
  const int mt = swz >> 2;
  const int nt = swz & 3;

  const int tid = threadIdx.x;
  const int lane = tid & 63;
  const int w = tid >> 6;
  const int wr = w >> 2, wc = w & 3;
  const int l15 = lane & 15, lh = lane >> 4;

  const int arow0 = mt * 256, brow0 = nt * 256;

  auto stage_half = [&](const unsigned short* __restrict__ src, int ldsOff,
                        int grow, int k0) {
#pragma unroll
    for (int i = 0; i < 2; ++i) {
      const int c = i * 512 + tid;
      const int r = c >> 3, ps = c & 7;
      load_lds16(src + (grow + r) * KDIM + k0 + ((ps ^ (r & 7)) * 8),
                 &lds[ldsOff + c * 8]);
    }
  };

  f32x4_t acc[8][4];
#pragma unroll
  for (int m = 0; m < 8; ++m)
#pragma unroll
    for (int n = 0; n < 4; ++n) acc[m][n] = (f32x4_t)0.0f;

  s16x8_t Af[8][2], Bf[4][2];

  auto rdA = [&](int pb, int m, int ks) -> s16x8_t {
    const int row = wr * 128 + m * 16 + l15;
    return *reinterpret_cast<const s16x8_t*>(
        &lds[pb + row * 64 + (((ks * 4 + lh) ^ (row & 7)) * 8)]);
  };
  auto rdB = [&](int pb, int n, int ks) -> s16x8_t {
    const int row = wc * 64 + n * 16 + l15;
    return *reinterpret_cast<const s16x8_t*>(
        &lds[pb + 16384 + row * 64 + (((ks * 4 + lh) ^ (row & 7)) * 8)]);
  };
  auto quad = [&](int mb, int nl) {
    __builtin_amdgcn_s_setprio(1);
#pragma unroll
    for (int m = 0; m < 4; ++m)
#pragma unroll
      for (int n = 0; n < 2; ++n)
#pragma unroll
        for (int ks = 0; ks < 2; ++ks)
          acc[mb + m][nl + n] = __builtin_amdgcn_mfma_f32_16x16x32_bf16(
              __builtin_bit_cast(bf16x8_t, Af[mb + m][ks]),
              __builtin_bit_cast(bf16x8_t, Bf[nl + n][ks]),
              acc[mb + m][nl + n], 0, 0, 0);
    __builtin_amdgcn_s_setprio(0);
  };

  // prologue: kt0 all 4 halves -> buf0; kt1 A-halves -> buf1
  stage_half(A, 0,             arow0,       0);
  stage_half(A, 8192,          arow0 + 128, 0);
  stage_half(W, 16384,         brow0,       0);
  stage_half(W, 16384 + 8192,  brow0 + 128, 0);
  stage_half(A, 32768,         arow0,       64);
  stage_half(A, 32768 + 8192,  arow0 + 128, 64);
  asm volatile("s_waitcnt vmcnt(4)" ::: "memory");
  SBAR();
  BARRIER();

  for (int kt = 0; kt < 16; ++kt) {
    const int p = kt & 1;
    const int pb = p * 32768, qb = 32768 - pb;
    const int k1 = ((kt + 1) & 15) * 64;
    const int k2 = ((kt + 2) & 15) * 64;   // wrapped tail: junk reload, never read
#pragma unroll
    for (int m = 0; m < 4; ++m)
#pragma unroll
      for (int ks = 0; ks < 2; ++ks) Af[m][ks] = rdA(pb, m, ks);
#pragma unroll
    for (int n = 0; n < 2; ++n)
#pragma unroll
      for (int ks = 0; ks < 2; ++ks) Bf[n][ks] = rdB(pb, n, ks);
    SBAR();                                         // pin group 1 (12 reads)
#pragma unroll
    for (int m = 0; m < 4; ++m)
#pragma unroll
      for (int ks = 0; ks < 2; ++ks) Af[4 + m][ks] = rdA(pb, 4 + m, ks);
    SBAR();                                         // pin group 2 (8 reads)
#pragma unroll
    for (int n = 2; n < 4; ++n)
#pragma unroll
      for (int ks = 0; ks < 2; ++ks) Bf[n][ks] = rdB(pb, n, ks);
    SBAR();                                         // pin group 3 (4 reads)
    stage_half(W, qb + 16384, brow0, k1);
    BARRIER();
    asm volatile("s_waitcnt lgkmcnt(12)" ::: "memory");  // group 1 done
    SBAR();
    quad(0, 0);
    BARRIER();
    stage_half(W, qb + 16384 + 8192, brow0 + 128, k1);
    BARRIER();
    asm volatile("s_waitcnt lgkmcnt(4)" ::: "memory");   // + group 2 done
    SBAR();
    quad(4, 0);
    BARRIER();
    stage_half(A, pb, arow0, k2);
    BARRIER();
    asm volatile("s_waitcnt lgkmcnt(0)" ::: "memory");   // last 4 done
    SBAR();
    quad(0, 2);
    BARRIER();
    stage_half(A, pb + 8192, arow0 + 128, k2);
    BARRIER();
    quad(4, 2);
    asm volatile("s_waitcnt vmcnt(4)" ::: "memory");     // kt+1 fully landed
    SBAR();
    BARRIER();
  }

  // epilogue: C/D layout col = lane&15, row = (lane>>4)*4 + j  [m89/m91]
#pragma unroll
  for (int n = 0; n < 4; ++n) {
    const int col = nt * 256 + wc * 64 + n * 16 + l15;
    const float bv2 = bias[col];
#pragma unroll
    for (int m = 0; m < 8; ++m) {
      const int row0 = mt * 256 + wr * 128 + m * 16 + lh * 4;
      if (outMode == 2) {
        const int b = row0 >> 13, tl = row0 & 8191;
        const int h = col >> 6, d = col & 63;
        s16x4_t o;
#pragma unroll
        for (int j = 0; j < 4; ++j) {
          float v = acc[m][n][j] + bv2;
          if (fmap) v = (v > 0.0f) ? (v + 1.0f) : __expf(v);
          o[j] = (short)f2bf_bits(v);
        }
        *reinterpret_cast<s16x4_t*>(Cout + (((b * 16 + h) * 64 + d) * 8192 + tl)) = o;
      } else {
#pragma unroll
        for (int j = 0; j < 4; ++j) {
          float v = acc[m][n][j] + bv2;
          if (fmap) v = (v > 0.0f) ? (v + 1.0f) : __expf(v);  // elu(x)+1
          Cout[(row0 + j) * NDIM + col] = f2bf_bits(v);
        }
      }
    }
  }
}

// ---------------------------------------------------------------- final GEMM (R15 verbatim)
__global__ __launch_bounds__(512, 2) void gemm_out(
    const unsigned short* __restrict__ A, const unsigned short* __restrict__ W,
    const float* __restrict__ bias, float* __restrict__ Cout) {
  __shared__ short lds[65536];
  const int bid = blockIdx.x;                     // 512 blocks
  const int swz = (bid & 7) * 64 + (bid >> 3);
  const int mt = swz >> 2;
  const int nt = swz & 3;

  const int tid = threadIdx.x;
  const int lane = tid & 63;
  const int w = tid >> 6;
  const int wr = w >> 2, wc = w & 3;
  const int l15 = lane & 15, lh = lane >> 4;

  const int arow0 = mt * 256, brow0 = nt * 256;

  auto stage_half = [&](const unsigned short* __restrict__ src, int ldsOff,
                        int grow, int k0) {
#pragma unroll
    for (int i = 0; i < 2; ++i) {
      const int c = i * 512 + tid;
      const int r = c >> 3, ps = c & 7;
      load_lds16(src + (grow + r) * KDIM + k0 + ((ps ^ (r & 7)) * 8),
                 &lds[ldsOff + c * 8]);
    }
  };

  f32x4_t acc[8][4];
#pragma unroll
  for (int m = 0; m < 8; ++m)
#pragma unroll
    for (int n = 0; n < 4; ++n) acc[m][n] = (f32x4_t)0.0f;

  s16x8_t Af[8][2], Bf[4][2];

  auto rdA = [&](int pb, int m, int ks) -> s16x8_t {
    const int row = wr * 128 + m * 16 + l15;
    return *reinterpret_cast<const s16x8_t*>(
        &lds[pb + row * 64 + (((ks * 4 + lh) ^ (row & 7)) * 8)]);
  };
  auto rdB = [&](int pb, int n, int ks) -> s16x8_t {
    const int row = wc * 64 + n * 16 + l15;
    return *reinterpret_cast<const s16x8_t*>(
        &lds[pb + 16384 + row * 64 + (((ks * 4 + lh) ^ (row & 7)) * 8)]);
  };
  auto quad = [&](int mb, int nl) {
    __builtin_amdgcn_s_setprio(1);
#pragma unroll
    for (int m = 0; m < 4; ++m)
#pragma unroll
      for (int n = 0; n < 2; ++n)
#pragma unroll
        for (int ks = 0; ks < 2; ++ks)
          acc[mb + m][nl + n] = __builtin_amdgcn_mfma_f32_16x16x32_bf16(
              __builtin_bit_cast(bf16x8_t, Af[mb + m][ks]),
              __builtin_bit_cast(bf16x8_t, Bf[nl + n][ks]),
              acc[mb + m][nl + n], 0, 0, 0);
    __builtin_amdgcn_s_setprio(0);
  };

  stage_half(A, 0,             arow0,       0);
  stage_half(A, 8192,          arow0 + 128, 0);
  stage_half(W, 16384,         brow0,       0);
  stage_half(W, 16384 + 8192,  brow0 + 128, 0);
  stage_half(A, 32768,         arow0,       64);
  stage_half(A, 32768 + 8192,  arow0 + 128, 64);
  asm volatile("s_waitcnt vmcnt(4)" ::: "memory");
  SBAR();
  BARRIER();

  for (int kt = 0; kt < 16; ++kt) {
    const int p = kt & 1;
    const int pb = p * 32768, qb = 32768 - pb;
    const int k1 = ((kt + 1) & 15) * 64;
    const int k2 = ((kt + 2) & 15) * 64;
#pragma unroll
    for (int m = 0; m < 4; ++m)
#pragma unroll
      for (int ks = 0; ks < 2; ++ks) Af[m][ks] = rdA(pb, m, ks);
#pragma unroll
    for (int n = 0; n < 2; ++n)
#pragma unroll
      for (int ks = 0; ks < 2; ++ks) Bf[n][ks] = rdB(pb, n, ks);
    SBAR();
#pragma unroll
    for (int m = 0; m < 4; ++m)
#pragma unroll
      for (int ks = 0; ks < 2; ++ks) Af[4 + m][ks] = rdA(pb, 4 + m, ks);
    SBAR();
#pragma unroll
    for (int n = 2; n < 4; ++n)
#pragma unroll
      for (int ks = 0; ks < 2; ++ks) Bf[n][ks] = rdB(pb, n, ks);
    SBAR();
    stage_half(W, qb + 16384, brow0, k1);
    BARRIER();
    asm volatile("s_waitcnt lgkmcnt(12)" ::: "memory");
    SBAR();
    quad(0, 0);
    BARRIER();
    stage_half(W, qb + 16384 + 8192, brow0 + 128, k1);
    BARRIER();
    asm volatile("s_waitcnt lgkmcnt(4)" ::: "memory");
    SBAR();
    quad(4, 0);
    BARRIER();
    stage_half(A, pb, arow0, k2);
    BARRIER();
    asm volatile("s_waitcnt lgkmcnt(0)" ::: "memory");
    SBAR();
    quad(0, 2);
    BARRIER();
    stage_half(A, pb + 8192, arow0 + 128, k2);
    BARRIER();
    quad(4, 2);
    asm volatile("s_waitcnt vmcnt(4)" ::: "memory");
    SBAR();
    BARRIER();
  }

#pragma unroll
  for (int n = 0; n < 4; ++n) {
    const int col = nt * 256 + wc * 64 + n * 16 + l15;
    const float bv = bias[col];
#pragma unroll
    for (int m = 0; m < 8; ++m) {
      const int row0 = mt * 256 + wr * 128 + m * 16 + lh * 4;
#pragma unroll
      for (int j = 0; j < 4; ++j)
        __builtin_nontemporal_store(acc[m][n][j] + bv,   // final f32: never re-read
                                    &Cout[(row0 + j) * NDIM + col]);
    }
  }
}

// ---------------------------------------------------------------- kv + k_sum (MFMA, streaming)
__global__ __launch_bounds__(256) void kv_ksum_mfma(
    const unsigned short* __restrict__ kT, const unsigned short* __restrict__ vT,
    float* __restrict__ kvT, float* __restrict__ ksum) {
  const int bid = blockIdx.x;
  const int bh = bid >> 4, ch = bid & 15;
  const int tid = threadIdx.x;
  const int lane = tid & 63, w = tid >> 6;
  const int l15 = lane & 15, lh = lane >> 4;
  const int dblk = (w >> 1) * 32, eblk = (w & 1) * 32;

  f32x4_t acc[2][2];
#pragma unroll
  for (int m = 0; m < 2; ++m)
#pragma unroll
    for (int n = 0; n < 2; ++n) acc[m][n] = (f32x4_t)0.0f;
  float ks0 = 0.f, ks1 = 0.f;

  const int tbase = ch * 512 + lh * 8;
  const unsigned short* ka = kT + (bh * 64 + dblk + l15) * 8192 + tbase;
  const unsigned short* va = vT + (bh * 64 + eblk + l15) * 8192 + tbase;

  for (int t0 = 0; t0 < 512; t0 += 32) {
    s16x8_t ar[2], br[2];
#pragma unroll
    for (int m = 0; m < 2; ++m)
      ar[m] = *reinterpret_cast<const s16x8_t*>(ka + m * 16 * 8192 + t0);
#pragma unroll
    for (int n = 0; n < 2; ++n)
      br[n] = *reinterpret_cast<const s16x8_t*>(va + n * 16 * 8192 + t0);
#pragma unroll
    for (int m = 0; m < 2; ++m)
#pragma unroll
      for (int n = 0; n < 2; ++n)
        acc[m][n] = __builtin_amdgcn_mfma_f32_16x16x32_bf16(
            __builtin_bit_cast(bf16x8_t, ar[m]),
            __builtin_bit_cast(bf16x8_t, br[n]), acc[m][n], 0, 0, 0);
    if (eblk == 0) {
#pragma unroll
      for (int i = 0; i < 8; ++i) ks0 += bf2f((unsigned short)ar[0][i]);
#pragma unroll
      for (int i = 0; i < 8; ++i) ks1 += bf2f((unsigned short)ar[1][i]);
    }
  }

  if (eblk == 0) {
    ks0 += __shfl_xor(ks0, 16); ks0 += __shfl_xor(ks0, 32);
    ks1 += __shfl_xor(ks1, 16); ks1 += __shfl_xor(ks1, 32);
    if (lh == 0) {
      atomicAdd(&ksum[bh * 64 + dblk + l15], ks0);
      atomicAdd(&ksum[bh * 64 + dblk + 16 + l15], ks1);
    }
  }
#pragma unroll
  for (int n = 0; n < 2; ++n) {
    const int e = eblk + n * 16 + l15;
#pragma unroll
    for (int m = 0; m < 2; ++m) {
      const int d0 = dblk + m * 16 + lh * 4;
#pragma unroll
      for (int j = 0; j < 4; ++j)
        atomicAdd(&kvT[(bh * 64 + e) * 64 + d0 + j], acc[m][n][j]);
    }
  }
}

// ---------------------------------------------------------------- out = q@kv / (q.ksum+eps)
__global__ __launch_bounds__(256) void attn_apply_kernel(
    const unsigned short* __restrict__ qf, const float* __restrict__ kvT,
    const float* __restrict__ ksum, unsigned short* __restrict__ att) {
  const int bid = blockIdx.x;                     // 2048
  const int swz = (bid & 7) * 256 + (bid >> 3);
  const int bh = swz >> 5;
  const int tile = swz & 31;
  const int b = bh >> 4, h = bh & 15;
  const int tid = threadIdx.x;
  const int lane = tid & 63, w = tid >> 6;
  const int l15 = lane & 15, lh = lane >> 4;

  float ksr[16];
#pragma unroll
  for (int i = 0; i < 16; ++i) ksr[i] = ksum[bh * 64 + lh * 16 + i];

  bf16x8_t bfrag[2][4];
#pragma unroll
  for (int ks2 = 0; ks2 < 2; ++ks2)
#pragma unroll
    for (int n = 0; n < 4; ++n) {
      const float* p = kvT + (bh * 64 + n * 16 + l15) * 64 + ks2 * 32 + lh * 8;
      f32x4_t p0 = *reinterpret_cast<const f32x4_t*>(p);
      f32x4_t p1 = *reinterpret_cast<const f32x4_t*>(p + 4);
      s16x8_t t;
      t[0] = (short)f2bf_bits(p0[0]); t[1] = (short)f2bf_bits(p0[1]);
      t[2] = (short)f2bf_bits(p0[2]); t[3] = (short)f2bf_bits(p0[3]);
      t[4] = (short)f2bf_bits(p1[0]); t[5] = (short)f2bf_bits(p1[1]);
      t[6] = (short)f2bf_bits(p1[2]); t[7] = (short)f2bf_bits(p1[3]);
      bfrag[ks2][n] = __builtin_bit_cast(bf16x8_t, t);
    }

  const int rbase = b * 8192 + tile * 256 + w * 64;
  f32x4_t acc[4][4];
#pragma unroll
  for (int m = 0; m < 4; ++m)
#pragma unroll
    for (int n = 0; n < 4; ++n) acc[m][n] = (f32x4_t)0.0f;
  float rden[4][4];

#pragma unroll
  for (int m = 0; m < 4; ++m) {
    const int row = rbase + m * 16 + l15;
    const unsigned short* qrow = qf + row * 1024 + h * 64;
    bf16x8_t afr[2];
#pragma unroll
    for (int ks2 = 0; ks2 < 2; ++ks2)
      afr[ks2] = __builtin_bit_cast(bf16x8_t,
          *reinterpret_cast<const s16x8_t*>(qrow + ks2 * 32 + lh * 8));
    s16x8_t qa = *reinterpret_cast<const s16x8_t*>(qrow + lh * 16);
    s16x8_t qb = *reinterpret_cast<const s16x8_t*>(qrow + lh * 16 + 8);
    float part = 0.f;
#pragma unroll
    for (int i = 0; i < 8; ++i) part += bf2f((unsigned short)qa[i]) * ksr[i];
#pragma unroll
    for (int i = 0; i < 8; ++i) part += bf2f((unsigned short)qb[i]) * ksr[8 + i];
    part += __shfl_xor(part, 16);
    part += __shfl_xor(part, 32);
#pragma unroll
    for (int j = 0; j < 4; ++j) {
      float dj = __shfl(part, lh * 4 + j);
      rden[m][j] = 1.0f / (dj + EPSV);
    }
#pragma unroll
    for (int ks2 = 0; ks2 < 2; ++ks2)
#pragma unroll
      for (int n = 0; n < 4; ++n)
        acc[m][n] = __builtin_amdgcn_mfma_f32_16x16x32_bf16(afr[ks2], bfrag[ks2][n], acc[m][n], 0, 0, 0);
  }

#pragma unroll
  for (int m = 0; m < 4; ++m)
#pragma unroll
    for (int n = 0; n < 4; ++n) {
      const int col = h * 64 + n * 16 + l15;
#pragma unroll
      for (int j = 0; j < 4; ++j) {
        const int row = rbase + m * 16 + lh * 4 + j;
        att[row * 1024 + col] = f2bf_bits(acc[m][n][j] * rden[m][j]);
      }
    }
}

// ---------------------------------------------------------------- launch
extern "C" void kernel_launch(void* const* d_in, const int* in_sizes, int n_in,
                              void* d_out, int out_size, void* d_ws, size_t ws_size,
                              hipStream_t stream) {
  const float* query = (const float*)d_in[0];
  const float* key   = (const float*)d_in[1];
  const float* value = (const float*)d_in[2];
  const float* Wq = (const float*)d_in[3];
  const float* bq = (const float*)d_in[4];
  const float* Wk = (const float*)d_in[5];
  const float* bk = (const float*)d_in[6];
  const float* Wv = (const float*)d_in[7];
  const float* bv = (const float*)d_in[8];
  const float* Wo = (const float*)d_in[9];
  const float* bo = (const float*)d_in[10];
  float* out = (float*)d_out;

  if (ws_size < 277889024ULL) return;
  char* ws = (char*)d_ws;
  unsigned short* Vbf = (unsigned short*)(ws + 0);          // value bf16; reused as att
  unsigned short* qf  = (unsigned short*)(ws + 67108864);
  unsigned short* kTf = (unsigned short*)(ws + 134217728);  // k transposed [b][h][d][t]
  unsigned short* vTf = (unsigned short*)(ws + 201326592);  // v transposed
  unsigned short* Wqb = (unsigned short*)(ws + 268435456);
  unsigned short* Wkb = Wqb + 1048576;
  unsigned short* Wvb = Wkb + 1048576;
  unsigned short* Wob = Wvb + 1048576;
  float* kvT  = (float*)(ws + 276824064);
  float* ksum = (float*)(ws + 277872640);

  unsigned short* Qbf = (unsigned short*)d_out;   // d_out doubles as bf16 scratch
  unsigned short* Kbf = Qbf + 33554432;

  hipMemsetAsync(kvT, 0, (size_t)(64 * 64 * 64 + 64 * 64) * sizeof(float), stream);

  convert_all_f32_bf16<<<8192, 256, 0, stream>>>(
      query, key, value, Wq, Wk, Wv, Wo,
      Qbf, Kbf, Vbf, Wqb, Wkb, Wvb, Wob);

  gemm_qkv<<<1536, 512, 0, stream>>>(Qbf, Kbf, Vbf, Wqb, Wkb, Wvb,
                                     bq, bk, bv, qf, kTf, vTf);

  kv_ksum_mfma<<<1024, 256, 0, stream>>>(kTf, vTf, kvT, ksum);

  attn_apply_kernel<<<2048, 256, 0, stream>>>(qf, kvT, ksum, Vbf);  // att -> Vbf

  gemm_out<<<512, 512, 0, stream>>>(Vbf, Wob, bo, out);  // final -> f32
}